// Round 6
// baseline (932.587 us; speedup 1.0000x reference)
//
#include <hip/hip_runtime.h>
#include <hip/hip_bf16.h>

#define K_TOT 4096
#define N_TOT 11008
#define LDP 72

typedef __bf16 bf16x8 __attribute__((ext_vector_type(8)));
typedef float  f32x4  __attribute__((ext_vector_type(4)));
typedef float  f32x8  __attribute__((ext_vector_type(8)));

typedef __attribute__((address_space(1))) unsigned gu32;
typedef __attribute__((address_space(3))) unsigned lu32;

__device__ __forceinline__ void gload_lds16(const void* g, void* l) {
    __builtin_amdgcn_global_load_lds((gu32*)g, (lu32*)l, 16, 0, 0);
}

// ---------- prepass 1: dequant packed int4 -> bf16 W[N][K] ----------
__global__ __launch_bounds__(256)
void dequant_w(const int* __restrict__ Qw, const float* __restrict__ Sc,
               const float* __restrict__ Zr, __bf16* __restrict__ Wb)
{
    const int t   = blockIdx.x * 256 + threadIdx.x;
    const int c8  = t & (K_TOT / 8 - 1);
    const int r4  = t >> 9;
    const int kp0 = c8 * 8;
    const int n   = r4 * 4 + ((kp0 >> 4) & 3);
    const int kq  = kp0 >> 6;
    const int hf  = (kp0 >> 3) & 1;
    const int kb  = kq * 64 + hf * 32;

    const int4 wa = *(const int4*)(Qw + (size_t)r4 * K_TOT + kp0);
    const int4 wb = *(const int4*)(Qw + (size_t)r4 * K_TOT + kp0 + 4);
    const int g = kb >> 7;
    const float s = Sc[(size_t)g * N_TOT + n];
    const float z = Zr[(size_t)g * N_TOT + n];

    const int w8[8] = {wa.x, wa.y, wa.z, wa.w, wb.x, wb.y, wb.z, wb.w};
    bf16x8 ov[4];
    #pragma unroll
    for (int uu = 0; uu < 8; ++uu) {
        const unsigned v = (unsigned)w8[uu] & 0xFFFFu;
        #pragma unroll
        for (int i = 0; i < 4; ++i)
            ov[i][uu] = (__bf16)fmaf((float)((v >> (4 * i)) & 0xFu), s, z);
    }
    __bf16* o = Wb + (size_t)n * K_TOT + kb;
    #pragma unroll
    for (int i = 0; i < 4; ++i) *(bf16x8*)(o + i * 8) = ov[i];
}

// ---------- prepass 2: X f32 -> bf16 ----------
__global__ __launch_bounds__(256)
void convert_x(const float* __restrict__ X, __bf16* __restrict__ Xb, long total8)
{
    const long t = (long)blockIdx.x * 256 + threadIdx.x;
    if (t >= total8) return;
    f32x8 v = *(const f32x8*)(X + t * 8);
    bf16x8 o;
    #pragma unroll
    for (int j = 0; j < 8; ++j) o[j] = (__bf16)v[j];
    *(bf16x8*)(Xb + t * 8) = o;
}

// ---------- main: 256x256x64, 8 waves, dbuf + counted vmcnt + T2 + 4-phase ----------
// phase (MH, KS): reads A-frags [MH*4..MH*4+3]@KS (+B-frags@KS when MH==0),
// barrier, lgkmcnt(0)+sched_barrier (rule #18), setprio, 16 MFMA.
#define PHASE(MH, KS, READ_B)                                                   \
  {                                                                             \
    const unsigned cb = ((unsigned)((KS) * 64 + lhi * 16)) ^ rswz;              \
    bf16x8 afL[4];                                                              \
    _Pragma("unroll")                                                           \
    for (int j = 0; j < 4; ++j)                                                 \
      afL[j] = *(const bf16x8*)(cur + (wm + ((MH) * 4 + j) * 16 + l15) * 128 + cb); \
    if (READ_B) {                                                               \
      _Pragma("unroll")                                                         \
      for (int ni = 0; ni < 4; ++ni)                                            \
        bfv[ni] = *(const bf16x8*)(cur + 32768 + (wn + ni * 16 + l15) * 128 + cb); \
    }                                                                           \
    __builtin_amdgcn_s_barrier();                                               \
    asm volatile("s_waitcnt lgkmcnt(0)" ::: "memory");                          \
    __builtin_amdgcn_sched_barrier(0);                                          \
    __builtin_amdgcn_s_setprio(1);                                              \
    _Pragma("unroll")                                                           \
    for (int j = 0; j < 4; ++j) {                                               \
      _Pragma("unroll")                                                         \
      for (int ni = 0; ni < 4; ++ni)                                            \
        acc[(MH) * 4 + j][ni] = __builtin_amdgcn_mfma_f32_16x16x32_bf16(        \
            afL[j], bfv[ni], acc[(MH) * 4 + j][ni], 0, 0, 0);                   \
    }                                                                           \
    __builtin_amdgcn_s_setprio(0);                                              \
  }

__global__ __launch_bounds__(512, 2)
void gemm256(const __bf16* __restrict__ A, const __bf16* __restrict__ B,
             const float* __restrict__ Bias, float* __restrict__ C, int gridM)
{
    extern __shared__ char lds_raw[];   // 131072 B: 2 bufs x [A 32K | B 32K]

    const int tid  = threadIdx.x;
    const int lane = tid & 63;
    const int wid  = tid >> 6;          // 0..7
    const int l15  = lane & 15;
    const int lhi  = lane >> 4;

    // T1: bijective XCD swizzle (nwg % 8 == 0 guaranteed by host guard)
    const int nwg = gridDim.x;
    int wg = blockIdx.x;
    if ((nwg & 7) == 0) wg = (wg & 7) * (nwg >> 3) + (wg >> 3);
    const int bx  = wg % gridM;
    const int by  = wg / gridM;
    const int bm0 = bx * 256;
    const int bn0 = by * 256;

    const int wm = (wid >> 2) * 128;    // 0 / 128
    const int wn = (wid & 3) * 64;      // 0/64/128/192

    // staging source: chunk = 8 rows x 64 cols; lane l -> row l>>3, pre-swizzled col
    const int sr   = lane >> 3;
    const int scol = ((lane & 7) ^ sr) * 8;

    const __bf16* ap[4]; const __bf16* bp[4];
    #pragma unroll
    for (int j = 0; j < 4; ++j) {
        const int c = wid * 4 + j;      // chunk 0..31
        ap[j] = A + (size_t)(bm0 + c * 8 + sr) * K_TOT + scol;
        bp[j] = B + (size_t)(bn0 + c * 8 + sr) * K_TOT + scol;
    }

    char* buf0 = lds_raw;
    char* buf1 = lds_raw + 65536;
    const int ldsoff = wid * 4096;

    const unsigned rswz = (unsigned)((l15 & 7) << 4);

    f32x4 acc[8][4] = {};

    // prologue: stage tile 0
    #pragma unroll
    for (int j = 0; j < 4; ++j) {
        gload_lds16(ap[j], buf0 + ldsoff + j * 1024);
        gload_lds16(bp[j], buf0 + 32768 + ldsoff + j * 1024);
    }

    char* cur = buf0; char* nxt = buf1;
    const int NT = K_TOT / 64;
    for (int t = 0; t < NT; ++t) {
        if (t + 1 < NT) {
            const int k1 = (t + 1) * 64;
            #pragma unroll
            for (int j = 0; j < 4; ++j) {
                gload_lds16(ap[j] + k1, nxt + ldsoff + j * 1024);
                gload_lds16(bp[j] + k1, nxt + 32768 + ldsoff + j * 1024);
            }
            asm volatile("s_waitcnt vmcnt(8)" ::: "memory");  // tile t landed; t+1 in flight
        } else {
            asm volatile("s_waitcnt vmcnt(0)" ::: "memory");
        }
        __builtin_amdgcn_s_barrier();       // tile t visible to all waves
        __builtin_amdgcn_sched_barrier(0);

        {
            bf16x8 bfv[4];                  // B-frags held across the mh pair
            PHASE(0, 0, true)
            PHASE(1, 0, false)
            PHASE(0, 1, true)
            PHASE(1, 1, false)
        }

        asm volatile("" ::: "memory");
        __builtin_amdgcn_s_barrier();       // reads done before cur is re-staged
        __builtin_amdgcn_sched_barrier(0);
        char* tmp = cur; cur = nxt; nxt = tmp;
    }

    // epilogue
    #pragma unroll
    for (int ni = 0; ni < 4; ++ni) {
        const int col = bn0 + wn + ni * 16 + l15;
        const float bv = Bias[col];
        #pragma unroll
        for (int mi = 0; mi < 8; ++mi) {
            const int row = bm0 + wm + mi * 16 + lhi * 4;
            #pragma unroll
            for (int r = 0; r < 4; ++r)
                C[(size_t)(row + r) * N_TOT + col] = acc[mi][ni][r] + bv;
        }
    }
}

// ---------- fallback: round-3 fused kernel ----------
__global__ __launch_bounds__(256)
void qgemm_fused(const float* __restrict__ X, const int* __restrict__ Qw,
                 const float* __restrict__ Sc, const float* __restrict__ Zr,
                 const float* __restrict__ Bias, float* __restrict__ C)
{
    __shared__ __bf16 As[128][LDP];
    __shared__ __bf16 Bs[128][LDP];

    const int tid  = threadIdx.x;
    const int lane = tid & 63;
    const int wid  = tid >> 6;
    const int l15  = lane & 15;
    const int lhi  = lane >> 4;

    const int bm0 = blockIdx.x * 128;
    const int bn0 = blockIdx.y * 128;
    const int wm  = (wid >> 1) * 64;
    const int wn  = (wid & 1) * 64;

    const int ar = tid >> 3;
    const int ac = (tid & 7) * 8;

    const int nl   = tid >> 1;
    const int half = tid & 1;
    const int n_g  = bn0 + nl;
    const int* qptr = Qw + (size_t)(n_g >> 2) * K_TOT + (nl & 3) * 16 + half * 8;
    const float* scp = Sc + n_g;
    const float* zrp = Zr + n_g;

    f32x4 acc[4][4] = {};

    for (int kt = 0; kt < K_TOT / 64; ++kt) {
        const int k0 = kt * 64;
        const int4 wa = *(const int4*)(qptr + k0);
        const int4 wb = *(const int4*)(qptr + k0 + 4);
        const float s = scp[(size_t)(kt >> 1) * N_TOT];
        const float z = zrp[(size_t)(kt >> 1) * N_TOT];

        f32x8 av[4];
        #pragma unroll
        for (int p = 0; p < 4; ++p)
            av[p] = *(const f32x8*)(X + (size_t)(bm0 + p * 32 + ar) * K_TOT + k0 + ac);

        const int w8[8] = {wa.x, wa.y, wa.z, wa.w, wb.x, wb.y, wb.z, wb.w};
        bf16x8 ov[4];
        #pragma unroll
        for (int uu = 0; uu < 8; ++uu) {
            const unsigned v = (unsigned)w8[uu] & 0xFFFFu;
            #pragma unroll
            for (int i = 0; i < 4; ++i)
                ov[i][uu] = (__bf16)fmaf((float)((v >> (4 * i)) & 0xFu), s, z);
        }
        #pragma unroll
        for (int p = 0; p < 4; ++p) {
            bf16x8 ab;
            #pragma unroll
            for (int j = 0; j < 8; ++j) ab[j] = (__bf16)av[p][j];
            *(bf16x8*)&As[p * 32 + ar][ac] = ab;
        }
        #pragma unroll
        for (int cc = 0; cc < 4; ++cc)
            *(bf16x8*)&Bs[nl][half * 32 + cc * 8] = ov[cc];

        __syncthreads();

        #pragma unroll
        for (int ks = 0; ks < 2; ++ks) {
            bf16x8 af[4], bfr[4];
            const int kc = ks * 32 + lhi * 8;
            #pragma unroll
            for (int mi = 0; mi < 4; ++mi)
                af[mi] = *(const bf16x8*)&As[wm + mi * 16 + l15][kc];
            #pragma unroll
            for (int ni = 0; ni < 4; ++ni)
                bfr[ni] = *(const bf16x8*)&Bs[wn + ni * 16 + l15][kc];
            #pragma unroll
            for (int mi = 0; mi < 4; ++mi)
                #pragma unroll
                for (int ni = 0; ni < 4; ++ni)
                    acc[mi][ni] = __builtin_amdgcn_mfma_f32_16x16x32_bf16(
                        af[mi], bfr[ni], acc[mi][ni], 0, 0, 0);
        }
        __syncthreads();
    }

    #pragma unroll
    for (int ni = 0; ni < 4; ++ni) {
        const int col = bn0 + wn + ni * 16 + l15;
        const float bv = Bias[col];
        #pragma unroll
        for (int mi = 0; mi < 4; ++mi) {
            const int row = bm0 + wm + mi * 16 + lhi * 4;
            #pragma unroll
            for (int r = 0; r < 4; ++r)
                C[(size_t)(row + r) * N_TOT + col] = acc[mi][ni][r] + bv;
        }
    }
}

extern "C" void kernel_launch(void* const* d_in, const int* in_sizes, int n_in,
                              void* d_out, int out_size, void* d_ws, size_t ws_size,
                              hipStream_t stream) {
    const float* X    = (const float*)d_in[0];
    const int*   Qw   = (const int*)d_in[1];
    const float* Sc   = (const float*)d_in[2];
    const float* Zr   = (const float*)d_in[3];
    const float* Bias = (const float*)d_in[4];
    float* C = (float*)d_out;

    const int M = in_sizes[0] / K_TOT;                 // 8192
    const size_t xb_bytes = (size_t)M * K_TOT * 2;
    const size_t wb_bytes = (size_t)N_TOT * K_TOT * 2;
    const size_t need = xb_bytes + wb_bytes;

    const int gridM = M / 256;
    const int nwg   = gridM * (N_TOT / 256);           // 32*43 = 1376

    if (ws_size >= need && (M & 255) == 0 && (nwg & 7) == 0) {
        __bf16* Xb = (__bf16*)d_ws;
        __bf16* Wb = (__bf16*)((char*)d_ws + xb_bytes);

        const int nW = (N_TOT / 4) * (K_TOT / 8);
        dequant_w<<<nW / 256, 256, 0, stream>>>(Qw, Sc, Zr, Wb);

        const long total8 = (long)M * K_TOT / 8;
        convert_x<<<(int)((total8 + 255) / 256), 256, 0, stream>>>(X, Xb, total8);

        (void)hipFuncSetAttribute((const void*)gemm256,
                                  hipFuncAttributeMaxDynamicSharedMemorySize, 131072);
        gemm256<<<dim3(nwg), dim3(512), 131072, stream>>>(Xb, Wb, Bias, C, gridM);
    } else {
        dim3 grid(M / 128, N_TOT / 128);
        qgemm_fused<<<grid, dim3(256), 0, stream>>>(X, Qw, Sc, Zr, Bias, C);
    }
}

// Round 7
// 901.062 us; speedup vs baseline: 1.0350x; 1.0350x over previous
//
#include <hip/hip_runtime.h>
#include <hip/hip_bf16.h>

#define K_TOT 4096
#define N_TOT 11008
#define LDP 72

typedef __bf16 bf16x8 __attribute__((ext_vector_type(8)));
typedef float  f32x4  __attribute__((ext_vector_type(4)));
typedef float  f32x8  __attribute__((ext_vector_type(8)));
typedef float  f32x16 __attribute__((ext_vector_type(16)));

typedef __attribute__((address_space(1))) unsigned gu32;
typedef __attribute__((address_space(3))) unsigned lu32;

__device__ __forceinline__ void gload_lds16(const void* g, void* l) {
    __builtin_amdgcn_global_load_lds((gu32*)g, (lu32*)l, 16, 0, 0);
}

// ---------- prepass 1: dequant packed int4 -> bf16 W[N][K] ----------
__global__ __launch_bounds__(256)
void dequant_w(const int* __restrict__ Qw, const float* __restrict__ Sc,
               const float* __restrict__ Zr, __bf16* __restrict__ Wb)
{
    const int t   = blockIdx.x * 256 + threadIdx.x;
    const int c8  = t & (K_TOT / 8 - 1);
    const int r4  = t >> 9;
    const int kp0 = c8 * 8;
    const int n   = r4 * 4 + ((kp0 >> 4) & 3);
    const int kq  = kp0 >> 6;
    const int hf  = (kp0 >> 3) & 1;
    const int kb  = kq * 64 + hf * 32;

    const int4 wa = *(const int4*)(Qw + (size_t)r4 * K_TOT + kp0);
    const int4 wb = *(const int4*)(Qw + (size_t)r4 * K_TOT + kp0 + 4);
    const int g = kb >> 7;
    const float s = Sc[(size_t)g * N_TOT + n];
    const float z = Zr[(size_t)g * N_TOT + n];

    const int w8[8] = {wa.x, wa.y, wa.z, wa.w, wb.x, wb.y, wb.z, wb.w};
    bf16x8 ov[4];
    #pragma unroll
    for (int uu = 0; uu < 8; ++uu) {
        const unsigned v = (unsigned)w8[uu] & 0xFFFFu;
        #pragma unroll
        for (int i = 0; i < 4; ++i)
            ov[i][uu] = (__bf16)fmaf((float)((v >> (4 * i)) & 0xFu), s, z);
    }
    __bf16* o = Wb + (size_t)n * K_TOT + kb;
    #pragma unroll
    for (int i = 0; i < 4; ++i) *(bf16x8*)(o + i * 8) = ov[i];
}

// ---------- prepass 2: X f32 -> bf16 ----------
__global__ __launch_bounds__(256)
void convert_x(const float* __restrict__ X, __bf16* __restrict__ Xb, long total8)
{
    const long t = (long)blockIdx.x * 256 + threadIdx.x;
    if (t >= total8) return;
    f32x8 v = *(const f32x8*)(X + t * 8);
    bf16x8 o;
    #pragma unroll
    for (int j = 0; j < 8; ++j) o[j] = (__bf16)v[j];
    *(bf16x8*)(Xb + t * 8) = o;
}

// ---------- main: 256x256x64, 8 waves, dbuf + counted vmcnt + T2 + MFMA 32x32x16 ----------
__global__ __launch_bounds__(512, 2)
void gemm256(const __bf16* __restrict__ A, const __bf16* __restrict__ B,
             const float* __restrict__ Bias, float* __restrict__ C, int gridM)
{
    extern __shared__ char lds_raw[];   // 131072 B: 2 bufs x [A 32K | B 32K]

    const int tid  = threadIdx.x;
    const int lane = tid & 63;
    const int wid  = tid >> 6;          // 0..7
    const int l31  = lane & 31;
    const int h16  = (lane >> 5) * 16;  // k-half byte offset within 32-byte k-slice

    // T1: bijective XCD swizzle (nwg % 8 == 0 guaranteed by host guard)
    const int nwg = gridDim.x;
    int wg = blockIdx.x;
    if ((nwg & 7) == 0) wg = (wg & 7) * (nwg >> 3) + (wg >> 3);
    const int bx  = wg % gridM;
    const int by  = wg / gridM;
    const int bm0 = bx * 256;
    const int bn0 = by * 256;

    const int wm = (wid >> 2) * 128;    // 0 / 128
    const int wn = (wid & 3) * 64;      // 0/64/128/192

    // staging source: chunk = 8 rows x 64 cols; lane l -> row l>>3, pre-swizzled col
    const int sr   = lane >> 3;
    const int scol = ((lane & 7) ^ sr) * 8;

    const __bf16* ap[4]; const __bf16* bp[4];
    #pragma unroll
    for (int j = 0; j < 4; ++j) {
        const int c = wid * 4 + j;      // chunk 0..31
        ap[j] = A + (size_t)(bm0 + c * 8 + sr) * K_TOT + scol;
        bp[j] = B + (size_t)(bn0 + c * 8 + sr) * K_TOT + scol;
    }

    char* buf0 = lds_raw;
    char* buf1 = lds_raw + 65536;
    const int ldsoff = wid * 4096;

    const unsigned rswz = (unsigned)((lane & 7) << 4);   // row&7 == lane&7 for our rows

    f32x16 acc[4][2] = {};

    // prologue: stage tile 0
    #pragma unroll
    for (int j = 0; j < 4; ++j) {
        gload_lds16(ap[j], buf0 + ldsoff + j * 1024);
        gload_lds16(bp[j], buf0 + 32768 + ldsoff + j * 1024);
    }

    char* cur = buf0; char* nxt = buf1;
    const int NT = K_TOT / 64;
    for (int t = 0; t < NT; ++t) {
        if (t + 1 < NT) {
            const int k1 = (t + 1) * 64;
            #pragma unroll
            for (int j = 0; j < 4; ++j) {
                gload_lds16(ap[j] + k1, nxt + ldsoff + j * 1024);
                gload_lds16(bp[j] + k1, nxt + 32768 + ldsoff + j * 1024);
            }
            asm volatile("s_waitcnt vmcnt(8)" ::: "memory");  // tile t landed; t+1 in flight
        } else {
            asm volatile("s_waitcnt vmcnt(0)" ::: "memory");
        }
        __builtin_amdgcn_s_barrier();
        __builtin_amdgcn_sched_barrier(0);

        // 4 k-slices of K=16; per slice: 4 A-frags (32 rows each), 2 B-frags, 8 MFMA
        #pragma unroll
        for (int ks = 0; ks < 4; ++ks) {
            const unsigned cb = ((unsigned)(ks * 32 + h16)) ^ rswz;
            bf16x8 af[4], bfv[2];
            #pragma unroll
            for (int mt = 0; mt < 4; ++mt)
                af[mt] = *(const bf16x8*)(cur + (wm + mt * 32 + l31) * 128 + cb);
            #pragma unroll
            for (int nt = 0; nt < 2; ++nt)
                bfv[nt] = *(const bf16x8*)(cur + 32768 + (wn + nt * 32 + l31) * 128 + cb);
            __builtin_amdgcn_s_setprio(1);
            #pragma unroll
            for (int mt = 0; mt < 4; ++mt)
                #pragma unroll
                for (int nt = 0; nt < 2; ++nt)
                    acc[mt][nt] = __builtin_amdgcn_mfma_f32_32x32x16_bf16(
                        af[mt], bfv[nt], acc[mt][nt], 0, 0, 0);
            __builtin_amdgcn_s_setprio(0);
        }

        asm volatile("" ::: "memory");
        __builtin_amdgcn_s_barrier();       // reads done before cur is re-staged
        __builtin_amdgcn_sched_barrier(0);
        char* tmp = cur; cur = nxt; nxt = tmp;
    }

    // epilogue: 32x32 C/D layout (m74/m101): col = lane&31,
    // row = (reg&3) + 8*(reg>>2) + 4*(lane>>5)
    const int rlo = 4 * (lane >> 5);
    #pragma unroll
    for (int nt = 0; nt < 2; ++nt) {
        const int col = bn0 + wn + nt * 32 + l31;
        const float bv = Bias[col];
        #pragma unroll
        for (int mt = 0; mt < 4; ++mt) {
            const int rowb = bm0 + wm + mt * 32 + rlo;
            #pragma unroll
            for (int r = 0; r < 16; ++r) {
                const int row = rowb + (r & 3) + 8 * (r >> 2);
                C[(size_t)row * N_TOT + col] = acc[mt][nt][r] + bv;
            }
        }
    }
}

// ---------- fallback: round-3 fused kernel ----------
__global__ __launch_bounds__(256)
void qgemm_fused(const float* __restrict__ X, const int* __restrict__ Qw,
                 const float* __restrict__ Sc, const float* __restrict__ Zr,
                 const float* __restrict__ Bias, float* __restrict__ C)
{
    __shared__ __bf16 As[128][LDP];
    __shared__ __bf16 Bs[128][LDP];

    const int tid  = threadIdx.x;
    const int lane = tid & 63;
    const int wid  = tid >> 6;
    const int l15  = lane & 15;
    const int lhi  = lane >> 4;

    const int bm0 = blockIdx.x * 128;
    const int bn0 = blockIdx.y * 128;
    const int wm  = (wid >> 1) * 64;
    const int wn  = (wid & 1) * 64;

    const int ar = tid >> 3;
    const int ac = (tid & 7) * 8;

    const int nl   = tid >> 1;
    const int half = tid & 1;
    const int n_g  = bn0 + nl;
    const int* qptr = Qw + (size_t)(n_g >> 2) * K_TOT + (nl & 3) * 16 + half * 8;
    const float* scp = Sc + n_g;
    const float* zrp = Zr + n_g;

    f32x4 acc[4][4] = {};

    for (int kt = 0; kt < K_TOT / 64; ++kt) {
        const int k0 = kt * 64;
        const int4 wa = *(const int4*)(qptr + k0);
        const int4 wb = *(const int4*)(qptr + k0 + 4);
        const float s = scp[(size_t)(kt >> 1) * N_TOT];
        const float z = zrp[(size_t)(kt >> 1) * N_TOT];

        f32x8 av[4];
        #pragma unroll
        for (int p = 0; p < 4; ++p)
            av[p] = *(const f32x8*)(X + (size_t)(bm0 + p * 32 + ar) * K_TOT + k0 + ac);

        const int w8[8] = {wa.x, wa.y, wa.z, wa.w, wb.x, wb.y, wb.z, wb.w};
        bf16x8 ov[4];
        #pragma unroll
        for (int uu = 0; uu < 8; ++uu) {
            const unsigned v = (unsigned)w8[uu] & 0xFFFFu;
            #pragma unroll
            for (int i = 0; i < 4; ++i)
                ov[i][uu] = (__bf16)fmaf((float)((v >> (4 * i)) & 0xFu), s, z);
        }
        #pragma unroll
        for (int p = 0; p < 4; ++p) {
            bf16x8 ab;
            #pragma unroll
            for (int j = 0; j < 8; ++j) ab[j] = (__bf16)av[p][j];
            *(bf16x8*)&As[p * 32 + ar][ac] = ab;
        }
        #pragma unroll
        for (int cc = 0; cc < 4; ++cc)
            *(bf16x8*)&Bs[nl][half * 32 + cc * 8] = ov[cc];

        __syncthreads();

        #pragma unroll
        for (int ks = 0; ks < 2; ++ks) {
            bf16x8 af[4], bfr[4];
            const int kc = ks * 32 + lhi * 8;
            #pragma unroll
            for (int mi = 0; mi < 4; ++mi)
                af[mi] = *(const bf16x8*)&As[wm + mi * 16 + l15][kc];
            #pragma unroll
            for (int ni = 0; ni < 4; ++ni)
                bfr[ni] = *(const bf16x8*)&Bs[wn + ni * 16 + l15][kc];
            #pragma unroll
            for (int mi = 0; mi < 4; ++mi)
                #pragma unroll
                for (int ni = 0; ni < 4; ++ni)
                    acc[mi][ni] = __builtin_amdgcn_mfma_f32_16x16x32_bf16(
                        af[mi], bfr[ni], acc[mi][ni], 0, 0, 0);
        }
        __syncthreads();
    }

    #pragma unroll
    for (int ni = 0; ni < 4; ++ni) {
        const int col = bn0 + wn + ni * 16 + l15;
        const float bv = Bias[col];
        #pragma unroll
        for (int mi = 0; mi < 4; ++mi) {
            const int row = bm0 + wm + mi * 16 + lhi * 4;
            #pragma unroll
            for (int r = 0; r < 4; ++r)
                C[(size_t)(row + r) * N_TOT + col] = acc[mi][ni][r] + bv;
        }
    }
}

extern "C" void kernel_launch(void* const* d_in, const int* in_sizes, int n_in,
                              void* d_out, int out_size, void* d_ws, size_t ws_size,
                              hipStream_t stream) {
    const float* X    = (const float*)d_in[0];
    const int*   Qw   = (const int*)d_in[1];
    const float* Sc   = (const float*)d_in[2];
    const float* Zr   = (const float*)d_in[3];
    const float* Bias = (const float*)d_in[4];
    float* C = (float*)d_out;

    const int M = in_sizes[0] / K_TOT;                 // 8192
    const size_t xb_bytes = (size_t)M * K_TOT * 2;
    const size_t wb_bytes = (size_t)N_TOT * K_TOT * 2;
    const size_t need = xb_bytes + wb_bytes;

    const int gridM = M / 256;
    const int nwg   = gridM * (N_TOT / 256);           // 32*43 = 1376

    if (ws_size >= need && (M & 255) == 0 && (nwg & 7) == 0) {
        __bf16* Xb = (__bf16*)d_ws;
        __bf16* Wb = (__bf16*)((char*)d_ws + xb_bytes);

        const int nW = (N_TOT / 4) * (K_TOT / 8);
        dequant_w<<<nW / 256, 256, 0, stream>>>(Qw, Sc, Zr, Wb);

        const long total8 = (long)M * K_TOT / 8;
        convert_x<<<(int)((total8 + 255) / 256), 256, 0, stream>>>(X, Xb, total8);

        (void)hipFuncSetAttribute((const void*)gemm256,
                                  hipFuncAttributeMaxDynamicSharedMemorySize, 131072);
        gemm256<<<dim3(nwg), dim3(512), 131072, stream>>>(Xb, Wb, Bias, C, gridM);
    } else {
        dim3 grid(M / 128, N_TOT / 128);
        qgemm_fused<<<grid, dim3(256), 0, stream>>>(X, Qw, Sc, Zr, Bias, C);
    }
}